// Round 1
// baseline (172.141 us; speedup 1.0000x reference)
//
#include <hip/hip_runtime.h>
#include <math.h>

#define NUM_EXPERTS 64
#define TOP_K 2

// ---------------------------------------------------------------------------
// Expansion: out[b*2+k][:] = x[b][:]  for k in {0,1}.
// float4 streaming: 1 read, 2 coalesced writes per thread, grid-stride.
// i indexes x in float4 units; col c = i % d4; dest rows 2b and 2b+1:
//   (2b)*d4 + c = 2*i - c,  (2b+1)*d4 + c = 2*i - c + d4.
// Consecutive lanes (consecutive i, same row) -> consecutive dst: coalesced.
// ---------------------------------------------------------------------------
__global__ void moe_expand_kernel(const float4* __restrict__ x4,
                                  float4* __restrict__ out4,
                                  int total4, int d4) {
    int stride = gridDim.x * blockDim.x;
    for (int i = blockIdx.x * blockDim.x + threadIdx.x; i < total4; i += stride) {
        float4 v = x4[i];
        int c = i % d4;           // d4 = 1024 (power of 2 -> compiler uses AND)
        int dst = 2 * i - c;      // max 2*16M fits in int32
        out4[dst]      = v;
        out4[dst + d4] = v;
    }
}

// ---------------------------------------------------------------------------
// Router: one 64-lane wave per row, one lane per expert (NUM_EXPERTS == 64).
// Full softmax + top-2 argmax on probs in double so near-tie index selection
// matches the numpy (float64) reference; ties break to the lower index, same
// as jax.lax.top_k. Renormalized weights = p / (p1 + p2).
// ---------------------------------------------------------------------------
__global__ void moe_router_kernel(const float* __restrict__ logits,
                                  float* __restrict__ idx_out,
                                  float* __restrict__ w_out,
                                  int batch) {
    int gid  = blockIdx.x * blockDim.x + threadIdx.x;
    int row  = gid >> 6;
    int lane = threadIdx.x & 63;
    if (row >= batch) return;

    double l = (double)logits[row * NUM_EXPERTS + lane];

    // wave max (butterfly; all lanes converge to identical value)
    double m = l;
    for (int off = 32; off; off >>= 1) {
        double o = __shfl_xor(m, off);
        m = (o > m) ? o : m;
    }
    double e = exp(l - m);
    double z = e;
    for (int off = 32; off; off >>= 1) z += __shfl_xor(z, off);
    double p = e / z;

    // top-1 argmax: lexicographic (value desc, index asc) — commutative+assoc,
    // so butterfly reduce is valid and matches top_k tie-breaking.
    double v1 = p; int i1 = lane;
    for (int off = 1; off < 64; off <<= 1) {
        double ov = __shfl_xor(v1, off);
        int    oi = __shfl_xor(i1, off);
        if (ov > v1 || (ov == v1 && oi < i1)) { v1 = ov; i1 = oi; }
    }
    // top-2: exclude winner (probs >= 0, so -1 acts as -inf)
    double v2 = (lane == i1) ? -1.0 : p; int i2 = lane;
    for (int off = 1; off < 64; off <<= 1) {
        double ov = __shfl_xor(v2, off);
        int    oi = __shfl_xor(i2, off);
        if (ov > v2 || (ov == v2 && oi < i2)) { v2 = ov; i2 = oi; }
    }

    if (lane == 0) {
        double s = v1 + v2;
        idx_out[2 * row]     = (float)i1;   // indices emitted as float32
        idx_out[2 * row + 1] = (float)i2;
        w_out[2 * row]       = (float)(v1 / s);
        w_out[2 * row + 1]   = (float)(v2 / s);
    }
}

extern "C" void kernel_launch(void* const* d_in, const int* in_sizes, int n_in,
                              void* d_out, int out_size, void* d_ws, size_t ws_size,
                              hipStream_t stream) {
    const float* x      = (const float*)d_in[0];
    const float* logits = (const float*)d_in[1];
    float* out = (float*)d_out;

    const int batch = in_sizes[1] / NUM_EXPERTS;     // 16384
    const int dim   = in_sizes[0] / batch;           // 4096
    const int d4    = dim / 4;                       // 1024

    const long long exp_elems = (long long)batch * TOP_K * dim;
    float* idx_out = out + exp_elems;                    // [B*K] as float
    float* w_out   = idx_out + (long long)batch * TOP_K; // [B*K]

    // memory-bound streaming: ~2048 blocks, grid-stride (G11)
    const int total4 = batch * d4;                   // 16,777,216 float4s
    moe_expand_kernel<<<2048, 256, 0, stream>>>(
        (const float4*)x, (float4*)out, total4, d4);

    // one wave per row
    const int rthreads = batch * 64;
    moe_router_kernel<<<(rthreads + 255) / 256, 256, 0, stream>>>(
        logits, idx_out, w_out, batch);
}